// Round 1
// baseline (2681.716 us; speedup 1.0000x reference)
//
#include <hip/hip_runtime.h>
#include <math.h>

#define B_ 32
#define S_ 64
#define H_ 300
#define L_ 20
#define G_ 1200          // 4H
#define M_ 2048          // B*S
#define EPSF 1e-8f

// ---------------- transpose (R x C) -> (C x R) ----------------
__global__ __launch_bounds__(256) void k_transpose(const float* __restrict__ src,
        float* __restrict__ dst, int R, int C) {
  __shared__ float t[32][33];
  int tx = threadIdx.x & 31, ty = threadIdx.x >> 5;
  int c0 = blockIdx.x * 32, r0 = blockIdx.y * 32;
  #pragma unroll
  for (int q = 0; q < 4; ++q) {
    int r = r0 + ty + q * 8, c = c0 + tx;
    t[ty + q * 8][tx] = (r < R && c < C) ? src[(size_t)r * C + c] : 0.f;
  }
  __syncthreads();
  #pragma unroll
  for (int q = 0; q < 4; ++q) {
    int c = c0 + ty + q * 8, r = r0 + tx;
    if (c < C && r < R) dst[(size_t)c * R + r] = t[tx][ty + q * 8];
  }
}

// ---- gate-interleave: WT (300 x 1200) -> WG [k][j][g] (float4 per (k,j)) ----
__global__ __launch_bounds__(256) void k_gateilv(const float* __restrict__ WT,
        float* __restrict__ WG) {
  int idx = blockIdx.x * 256 + threadIdx.x;   // k*300 + j
  if (idx >= 90000) return;
  int k = idx / 300, j = idx - k * 300;
  float4 v;
  v.x = WT[(size_t)k * 1200 + j];
  v.y = WT[(size_t)k * 1200 + 300 + j];
  v.z = WT[(size_t)k * 1200 + 600 + j];
  v.w = WT[(size_t)k * 1200 + 900 + j];
  *(float4*)(WG + (size_t)idx * 4) = v;
}

// ---------------- input-projection GEMM ----------------
// C[m,n] = sum_k A[row(m),k]*WT[k,n] + bias[n];  row(m)=gather[m] if gather.
__global__ __launch_bounds__(256) void k_proj(const float* __restrict__ A,
        const int* __restrict__ gather, const float* __restrict__ WT,
        const float* __restrict__ bias, float* __restrict__ Cout,
        int M, int N, int K, int lda) {
  __shared__ float As[16][66];
  __shared__ float Bs[16][66];
  int tid = threadIdx.x;
  int m0 = blockIdx.x * 64, n0 = blockIdx.y * 64;
  int tx = tid & 15, ty = tid >> 4;
  int ar = tid >> 2, ac = (tid & 3) * 4;
  int br = tid >> 4, bc = (tid & 15) * 4;
  int gm = m0 + ar;
  const float* Arow = gather ? (A + (size_t)gather[gm] * lda)
                             : (A + (size_t)gm * lda);
  float acc[4][4] = {};
  int nk = (K + 15) / 16;
  for (int kc = 0; kc < nk; ++kc) {
    int k0 = kc * 16;
    if (k0 + 16 <= K) {
      float4 av = *(const float4*)(Arow + k0 + ac);
      As[ac + 0][ar] = av.x; As[ac + 1][ar] = av.y;
      As[ac + 2][ar] = av.z; As[ac + 3][ar] = av.w;
    } else {
      #pragma unroll
      for (int q = 0; q < 4; ++q) {
        int k = k0 + ac + q;
        As[ac + q][ar] = (k < K) ? Arow[k] : 0.f;
      }
    }
    {
      int kk = k0 + br, n = n0 + bc;
      if (kk < K && n + 3 < N) {
        float4 bv = *(const float4*)(WT + (size_t)kk * N + n);
        Bs[br][bc + 0] = bv.x; Bs[br][bc + 1] = bv.y;
        Bs[br][bc + 2] = bv.z; Bs[br][bc + 3] = bv.w;
      } else {
        #pragma unroll
        for (int q = 0; q < 4; ++q) {
          int n2 = n + q;
          Bs[br][bc + q] = (kk < K && n2 < N) ? WT[(size_t)kk * N + n2] : 0.f;
        }
      }
    }
    __syncthreads();
    #pragma unroll
    for (int kk = 0; kk < 16; ++kk) {
      float av[4], bv[4];
      #pragma unroll
      for (int i = 0; i < 4; ++i) av[i] = As[kk][ty * 4 + i];
      #pragma unroll
      for (int j = 0; j < 4; ++j) bv[j] = Bs[kk][tx * 4 + j];
      #pragma unroll
      for (int i = 0; i < 4; ++i)
        #pragma unroll
        for (int j = 0; j < 4; ++j) acc[i][j] += av[i] * bv[j];
    }
    __syncthreads();
  }
  #pragma unroll
  for (int i = 0; i < 4; ++i) {
    int m = m0 + ty * 4 + i;
    #pragma unroll
    for (int j = 0; j < 4; ++j) {
      int n = n0 + tx * 4 + j;
      if (n < N) Cout[(size_t)m * N + n] = acc[i][j] + bias[n];
    }
  }
}

// ---------------- one LSTM timestep (4 recurrences batched) ----------------
// WG layout: [k][j][gate] float4.  Hbuf double-buffered (parity).
__global__ __launch_bounds__(256) void k_lstm(const float* __restrict__ XG,
        const float* __restrict__ WGf, const float* __restrict__ WGb,
        float* __restrict__ Hbuf, float* __restrict__ Cst,
        float* __restrict__ O, int t, int parity) {
  __shared__ float Hs[4 * 300];
  int rec = blockIdx.y, bt = blockIdx.z;
  const float4* WG = (const float4*)((rec & 1) ? WGb : WGf);
  int tt = (rec & 1) ? (S_ - 1 - t) : t;
  const float* Hin = Hbuf + (size_t)parity * 38400 + rec * 9600 + bt * 1200;
  float* Hout = Hbuf + (size_t)(parity ^ 1) * 38400 + rec * 9600 + bt * 1200;
  int tid = threadIdx.x;
  for (int i = tid; i < 1200; i += 256) Hs[i] = Hin[i];
  __syncthreads();
  int jl = tid & 63, bl = tid >> 6;
  int j = blockIdx.x * 64 + jl;
  if (j >= H_) return;
  float a0 = 0.f, a1 = 0.f, a2 = 0.f, a3 = 0.f;
  const float4* wp = WG + j;
  const float* hp = Hs + bl * 300;
  #pragma unroll 4
  for (int k = 0; k < 300; ++k) {
    float4 w = wp[k * 300];
    float h = hp[k];
    a0 += h * w.x; a1 += h * w.y; a2 += h * w.z; a3 += h * w.w;
  }
  int b = bt * 4 + bl;
  size_t row = (size_t)rec * M_ + (size_t)b * S_ + tt;
  const float* xg = XG + row * 1200 + j;
  float zi = a0 + xg[0];
  float zf = a1 + xg[300];
  float zg = a2 + xg[600];
  float zo = a3 + xg[900];
  size_t ci = (size_t)rec * 9600 + (size_t)b * 300 + j;
  float c = Cst[ci];
  float si = 1.f / (1.f + expf(-zi));
  float sf = 1.f / (1.f + expf(-zf));
  float tg = tanhf(zg);
  float so = 1.f / (1.f + expf(-zo));
  float cn = sf * c + si * tg;
  float hn = so * tanhf(cn);
  Cst[ci] = cn;
  Hout[bl * 300 + j] = hn;
  if (O) O[row * 300 + j] = hn;
}

// ---------------- plain L2 norms of the 4 ctx outputs ----------------
__global__ __launch_bounds__(256) void k_norms(const float* __restrict__ O,
        float* __restrict__ NRM) {
  int idx = blockIdx.x * 4 + (threadIdx.x >> 6);
  int lane = threadIdx.x & 63;
  const float* p = O + (size_t)idx * 300;
  float s = 0.f;
  for (int h = lane; h < 300; h += 64) { float v = p[h]; s += v * v; }
  #pragma unroll
  for (int off = 32; off; off >>= 1) s += __shfl_xor(s, off);
  if (lane == 0) NRM[idx] = sqrtf(s);
}

// ---------------- cosine matrices ----------------
__global__ __launch_bounds__(256) void k_cos(const float* __restrict__ O,
        const float* __restrict__ NRM, float* __restrict__ COS) {
  int b = blockIdx.x, d = blockIdx.y;
  int r1 = d, r2 = 2 + d;
  const float* A = O + ((size_t)r1 * M_ + b * S_) * 300;
  const float* Bm = O + ((size_t)r2 * M_ + b * S_) * 300;
  __shared__ float As[64][33], Bs[64][33];
  int tid = threadIdx.x;
  int tx = tid & 15, ty = tid >> 4;
  int lr = tid >> 2, lc = (tid & 3) * 8;
  float acc[4][4] = {};
  for (int k0 = 0; k0 < 300; k0 += 32) {
    if (k0 + 32 <= 300) {
      float4 a0 = *(const float4*)(A + (size_t)lr * 300 + k0 + lc);
      float4 a1 = *(const float4*)(A + (size_t)lr * 300 + k0 + lc + 4);
      As[lr][lc + 0] = a0.x; As[lr][lc + 1] = a0.y; As[lr][lc + 2] = a0.z; As[lr][lc + 3] = a0.w;
      As[lr][lc + 4] = a1.x; As[lr][lc + 5] = a1.y; As[lr][lc + 6] = a1.z; As[lr][lc + 7] = a1.w;
      float4 b0 = *(const float4*)(Bm + (size_t)lr * 300 + k0 + lc);
      float4 b1 = *(const float4*)(Bm + (size_t)lr * 300 + k0 + lc + 4);
      Bs[lr][lc + 0] = b0.x; Bs[lr][lc + 1] = b0.y; Bs[lr][lc + 2] = b0.z; Bs[lr][lc + 3] = b0.w;
      Bs[lr][lc + 4] = b1.x; Bs[lr][lc + 5] = b1.y; Bs[lr][lc + 6] = b1.z; Bs[lr][lc + 7] = b1.w;
    } else {
      #pragma unroll
      for (int q = 0; q < 8; ++q) {
        int k = k0 + lc + q;
        As[lr][lc + q] = (k < 300) ? A[(size_t)lr * 300 + k] : 0.f;
        Bs[lr][lc + q] = (k < 300) ? Bm[(size_t)lr * 300 + k] : 0.f;
      }
    }
    __syncthreads();
    #pragma unroll
    for (int kk = 0; kk < 32; ++kk) {
      float av[4], bv[4];
      #pragma unroll
      for (int i = 0; i < 4; ++i) av[i] = As[ty * 4 + i][kk];
      #pragma unroll
      for (int j = 0; j < 4; ++j) bv[j] = Bs[tx * 4 + j][kk];
      #pragma unroll
      for (int i = 0; i < 4; ++i)
        #pragma unroll
        for (int j = 0; j < 4; ++j) acc[i][j] += av[i] * bv[j];
    }
    __syncthreads();
  }
  float n1[4], n2[4];
  #pragma unroll
  for (int i = 0; i < 4; ++i) {
    n1[i] = NRM[(size_t)r1 * M_ + b * S_ + ty * 4 + i];
    n2[i] = NRM[(size_t)r2 * M_ + b * S_ + tx * 4 + i];
  }
  float* outp = COS + ((size_t)d * 32 + b) * 4096;
  #pragma unroll
  for (int i = 0; i < 4; ++i)
    #pragma unroll
    for (int j = 0; j < 4; ++j)
      outp[(ty * 4 + i) * 64 + tx * 4 + j] = acc[i][j] / (n1[i] * n2[j]);
}

// ---------------- cos row/col sums ----------------
__global__ __launch_bounds__(64) void k_csum(const float* __restrict__ COS,
        float* __restrict__ RS, float* __restrict__ CS) {
  int b = blockIdx.x, d = blockIdx.y, t = threadIdx.x;
  const float* base = COS + ((size_t)d * 32 + b) * 4096;
  float rs = 0.f, cs = 0.f;
  for (int k = 0; k < 64; ++k) { rs += base[t * 64 + k]; cs += base[k * 64 + t]; }
  RS[(d * 32 + b) * 64 + t] = rs;   // sum over j (axis=2)
  CS[(d * 32 + b) * 64 + t] = cs;   // sum over i (axis=1)
}

// ---------------- pairwise match (normalized), PAIR[d][b][l][i][j] ----------------
__global__ __launch_bounds__(256) void k_pair(const float* __restrict__ O,
        const float* __restrict__ NRM, const float* __restrict__ Wf,
        const float* __restrict__ Wb, float* __restrict__ PAIR) {
  int b = blockIdx.x, l = blockIdx.y, d = blockIdx.z;
  int r1 = d;                       // s1f or s1b
  const float* A = O + ((size_t)r1 * M_ + b * S_) * 300;
  const float* Bm = O + ((size_t)3 * M_ + b * S_) * 300;   // s2b both dirs
  const float* Wl = (d ? Wb : Wf) + (size_t)l * 300;
  __shared__ float As[64][33], Bs[64][33];
  int tid = threadIdx.x;
  int tx = tid & 15, ty = tid >> 4;
  int lr = tid >> 2, lc = (tid & 3) * 8;
  float acc[4][4] = {};
  for (int k0 = 0; k0 < 300; k0 += 32) {
    if (k0 + 32 <= 300) {
      float4 a0 = *(const float4*)(A + (size_t)lr * 300 + k0 + lc);
      float4 a1 = *(const float4*)(A + (size_t)lr * 300 + k0 + lc + 4);
      float4 w0 = *(const float4*)(Wl + k0 + lc);
      float4 w1 = *(const float4*)(Wl + k0 + lc + 4);
      As[lr][lc + 0] = a0.x * w0.x * w0.x; As[lr][lc + 1] = a0.y * w0.y * w0.y;
      As[lr][lc + 2] = a0.z * w0.z * w0.z; As[lr][lc + 3] = a0.w * w0.w * w0.w;
      As[lr][lc + 4] = a1.x * w1.x * w1.x; As[lr][lc + 5] = a1.y * w1.y * w1.y;
      As[lr][lc + 6] = a1.z * w1.z * w1.z; As[lr][lc + 7] = a1.w * w1.w * w1.w;
      float4 b0 = *(const float4*)(Bm + (size_t)lr * 300 + k0 + lc);
      float4 b1 = *(const float4*)(Bm + (size_t)lr * 300 + k0 + lc + 4);
      Bs[lr][lc + 0] = b0.x; Bs[lr][lc + 1] = b0.y; Bs[lr][lc + 2] = b0.z; Bs[lr][lc + 3] = b0.w;
      Bs[lr][lc + 4] = b1.x; Bs[lr][lc + 5] = b1.y; Bs[lr][lc + 6] = b1.z; Bs[lr][lc + 7] = b1.w;
    } else {
      #pragma unroll
      for (int q = 0; q < 8; ++q) {
        int k = k0 + lc + q;
        float w = (k < 300) ? Wl[k] : 0.f;
        As[lr][lc + q] = (k < 300) ? A[(size_t)lr * 300 + k] * w * w : 0.f;
        Bs[lr][lc + q] = (k < 300) ? Bm[(size_t)lr * 300 + k] : 0.f;
      }
    }
    __syncthreads();
    #pragma unroll
    for (int kk = 0; kk < 32; ++kk) {
      float av[4], bv[4];
      #pragma unroll
      for (int i = 0; i < 4; ++i) av[i] = As[ty * 4 + i][kk];
      #pragma unroll
      for (int j = 0; j < 4; ++j) bv[j] = Bs[tx * 4 + j][kk];
      #pragma unroll
      for (int i = 0; i < 4; ++i)
        #pragma unroll
        for (int j = 0; j < 4; ++j) acc[i][j] += av[i] * bv[j];
    }
    __syncthreads();
  }
  float n1[4], n2[4];
  #pragma unroll
  for (int i = 0; i < 4; ++i) {
    n1[i] = NRM[(size_t)r1 * M_ + b * S_ + ty * 4 + i];
    n2[i] = NRM[(size_t)3 * M_ + b * S_ + tx * 4 + i];
  }
  float* outp = PAIR + (((size_t)d * 32 + b) * 20 + l) * 4096;
  #pragma unroll
  for (int i = 0; i < 4; ++i)
    #pragma unroll
    for (int j = 0; j < 4; ++j)
      outp[(ty * 4 + i) * 64 + tx * 4 + j] = acc[i][j] / (n1[i] * n2[j]);
}

// ---------------- maxpool over j -> V1 slot, over i -> V2 slot ----------------
__global__ __launch_bounds__(256) void k_pairmaxJ(const float* __restrict__ PAIR,
        float* __restrict__ V1) {
  int b = blockIdx.x, l = blockIdx.y, d = blockIdx.z;
  const float* P = PAIR + (((size_t)d * 32 + b) * 20 + l) * 4096;
  int lane = threadIdx.x & 63, ig = threadIdx.x >> 6;
  for (int i = ig; i < 64; i += 4) {
    float v = P[i * 64 + lane];
    #pragma unroll
    for (int off = 32; off; off >>= 1) v = fmaxf(v, __shfl_xor(v, off));
    if (lane == 0) V1[((size_t)b * S_ + i) * 160 + (d ? 100 : 20) + l] = v;
  }
}

__global__ __launch_bounds__(64) void k_pairmaxI(const float* __restrict__ PAIR,
        float* __restrict__ V2) {
  int b = blockIdx.x, l = blockIdx.y, d = blockIdx.z;
  const float* P = PAIR + (((size_t)d * 32 + b) * 20 + l) * 4096;
  int j = threadIdx.x;
  float m = -INFINITY;
  for (int i = 0; i < 64; ++i) m = fmaxf(m, P[i * 64 + j]);
  V2[((size_t)b * S_ + j) * 160 + (d ? 100 : 20) + l] = m;
}

// ---------------- mean/max attention vectors MM[v][b][r][h] ----------------
// v: 0 mean_s1_f 1 mean_s1_b 2 mean_s2_f 3 mean_s2_b 4..7 max variants same order
__global__ __launch_bounds__(128) void k_meanmax(const float* __restrict__ O,
        const float* __restrict__ COS, const float* __restrict__ RS,
        const float* __restrict__ CS, float* __restrict__ MM) {
  int b = blockIdx.x, rg = blockIdx.y, v = blockIdx.z;
  int isMax = v >> 2, vv = v & 3;
  int d = vv & 1, s2side = vv >> 1;
  int srcrec = s2side ? 0 : 2;      // s2-side uses s1f, s1-side uses s2f
  const float* SRC = O + ((size_t)srcrec * M_ + b * S_) * 300;
  const float* Cb = COS + ((size_t)d * 32 + b) * 4096;
  int tid = threadIdx.x;
  int h0 = tid, h1 = tid + 128, h2 = tid + 256;
  bool has2 = (h2 < 300);
  float init = isMax ? -INFINITY : 0.f;
  float acc[8][3];
  #pragma unroll
  for (int rr = 0; rr < 8; ++rr) { acc[rr][0] = init; acc[rr][1] = init; acc[rr][2] = init; }
  int r0 = rg * 8;
  for (int inner = 0; inner < 64; ++inner) {
    float s0 = SRC[(size_t)inner * 300 + h0];
    float s1 = SRC[(size_t)inner * 300 + h1];
    float s2v = has2 ? SRC[(size_t)inner * 300 + h2] : 0.f;
    #pragma unroll
    for (int rr = 0; rr < 8; ++rr) {
      int r = r0 + rr;
      float cv = s2side ? Cb[inner * 64 + r] : Cb[r * 64 + inner];
      if (isMax) {
        acc[rr][0] = fmaxf(acc[rr][0], cv * s0);
        acc[rr][1] = fmaxf(acc[rr][1], cv * s1);
        acc[rr][2] = fmaxf(acc[rr][2], cv * s2v);
      } else {
        acc[rr][0] += cv * s0; acc[rr][1] += cv * s1; acc[rr][2] += cv * s2v;
      }
    }
  }
  float* outp = MM + (size_t)v * 614400;
  for (int rr = 0; rr < 8; ++rr) {
    int r = r0 + rr;
    size_t o = ((size_t)b * S_ + r) * 300;
    if (isMax) {
      outp[o + h0] = acc[rr][0];
      outp[o + h1] = acc[rr][1];
      if (has2) outp[o + h2] = acc[rr][2];
    } else {
      float den = s2side ? CS[(d * 32 + b) * 64 + r] : RS[(d * 32 + b) * 64 + r];
      outp[o + h0] = acc[rr][0] / den;
      outp[o + h1] = acc[rr][1] / den;
      if (has2) outp[o + h2] = acc[rr][2] / den;
    }
  }
}

// ---------------- generic full-match (12 variants) ----------------
__global__ __launch_bounds__(256) void k_fullmatch(const float* __restrict__ O,
        const float* __restrict__ MM, const float* __restrict__ Wff,
        const float* __restrict__ Wfb, const float* __restrict__ Wat,
        const float* __restrict__ Wmx, float* __restrict__ V1, float* __restrict__ V2) {
  int item = blockIdx.x * 4 + (threadIdx.x >> 6);
  int lane = threadIdx.x & 63;
  int b = item >> 6, s = item & 63;
  int var = blockIdx.y;
  size_t ms = (size_t)b * S_ + s;
  const float* s1f = O;
  const float* s1b = O + (size_t)M_ * 300;
  const float* s2f = O + (size_t)2 * M_ * 300;
  const float* s2b = O + (size_t)3 * M_ * 300;
  const float *v1p, *v2p, *W;
  float* outp;
  switch (var) {
    case 0:  v1p = s1f + ms * 300; v2p = s2f + ((size_t)b * S_ + 63) * 300; W = Wff; outp = V1 + ms * 160 + 0;   break;
    case 1:  v1p = s1f + ms * 300; v2p = MM + (size_t)0 * 614400 + ms * 300; W = Wat; outp = V1 + ms * 160 + 40; break;
    case 2:  v1p = s1f + ms * 300; v2p = MM + (size_t)4 * 614400 + ms * 300; W = Wmx; outp = V1 + ms * 160 + 60; break;
    case 3:  v1p = s1b + ms * 300; v2p = s2b + ((size_t)b * S_ + 0) * 300;  W = Wfb; outp = V1 + ms * 160 + 80;  break;
    case 4:  v1p = s1b + ms * 300; v2p = MM + (size_t)1 * 614400 + ms * 300; W = Wat; outp = V1 + ms * 160 + 120; break;
    case 5:  v1p = s1b + ms * 300; v2p = MM + (size_t)5 * 614400 + ms * 300; W = Wmx; outp = V1 + ms * 160 + 140; break;
    case 6:  v1p = s2f + ms * 300; v2p = s1f + ((size_t)b * S_ + 63) * 300; W = Wff; outp = V2 + ms * 160 + 0;   break;
    case 7:  v1p = s2f + ms * 300; v2p = MM + (size_t)2 * 614400 + ms * 300; W = Wat; outp = V2 + ms * 160 + 40; break;
    case 8:  v1p = s2f + ms * 300; v2p = MM + (size_t)6 * 614400 + ms * 300; W = Wmx; outp = V2 + ms * 160 + 60; break;
    case 9:  v1p = s2b + ms * 300; v2p = s1b + ((size_t)b * S_ + 0) * 300;  W = Wfb; outp = V2 + ms * 160 + 80;  break;
    case 10: v1p = s2b + ms * 300; v2p = MM + (size_t)3 * 614400 + ms * 300; W = Wat; outp = V2 + ms * 160 + 120; break;
    default: v1p = s2b + ms * 300; v2p = MM + (size_t)7 * 614400 + ms * 300; W = Wmx; outp = V2 + ms * 160 + 140; break;
  }
  float av[5], bv[5], ab[5], a2[5], b2[5];
  #pragma unroll
  for (int q = 0; q < 5; ++q) {
    int h = lane + 64 * q;
    bool in = (h < 300);
    av[q] = in ? v1p[h] : 0.f;
    bv[q] = in ? v2p[h] : 0.f;
    ab[q] = av[q] * bv[q];
    a2[q] = av[q] * av[q];
    b2[q] = bv[q] * bv[q];
  }
  for (int l = 0; l < 20; ++l) {
    float sn = 0.f, sa = 0.f, sb = 0.f;
    #pragma unroll
    for (int q = 0; q < 5; ++q) {
      int h = lane + 64 * q;
      if (h < 300) {
        float w = W[(size_t)l * 300 + h];
        float w2 = w * w;
        sn += w2 * ab[q]; sa += w2 * a2[q]; sb += w2 * b2[q];
      }
    }
    #pragma unroll
    for (int off = 32; off; off >>= 1) {
      sn += __shfl_xor(sn, off);
      sa += __shfl_xor(sa, off);
      sb += __shfl_xor(sb, off);
    }
    if (lane == 0) {
      float n1 = fmaxf(sqrtf(sa), EPSF);
      float n2 = fmaxf(sqrtf(sb), EPSF);
      outp[l] = sn / (n1 * n2);
    }
  }
}

// ---------------- final MLP + log_softmax ----------------
__global__ __launch_bounds__(256) void k_mlp(const float* __restrict__ Hst,
        const float* __restrict__ W1T, const float* __restrict__ b1,
        const float* __restrict__ W2, const float* __restrict__ b2,
        float* __restrict__ out) {
  int b = blockIdx.x, tid = threadIdx.x;
  __shared__ float mvs[1200];
  __shared__ float xs[600];
  __shared__ float red[2][4];
  for (int i = tid; i < 1200; i += 256) {
    int r = i / 300, h = i - r * 300;
    mvs[i] = Hst[(size_t)r * 9600 + b * 300 + h];
  }
  __syncthreads();
  for (int o = tid; o < 600; o += 256) {
    float dot = b1[o];
    for (int k = 0; k < 1200; ++k) dot += mvs[k] * W1T[(size_t)k * 600 + o];
    xs[o] = tanhf(dot);
  }
  __syncthreads();
  float p0 = 0.f, p1 = 0.f;
  for (int k = tid; k < 600; k += 256) {
    float xv = xs[k];
    p0 += xv * W2[k];
    p1 += xv * W2[600 + k];
  }
  #pragma unroll
  for (int off = 32; off; off >>= 1) { p0 += __shfl_xor(p0, off); p1 += __shfl_xor(p1, off); }
  int w = tid >> 6;
  if ((tid & 63) == 0) { red[0][w] = p0; red[1][w] = p1; }
  __syncthreads();
  if (tid == 0) {
    float l0 = red[0][0] + red[0][1] + red[0][2] + red[0][3] + b2[0];
    float l1 = red[1][0] + red[1][1] + red[1][2] + red[1][3] + b2[1];
    float m = fmaxf(l0, l1);
    float lse = m + logf(expf(l0 - m) + expf(l1 - m));
    out[b * 2 + 0] = l0 - lse;
    out[b * 2 + 1] = l1 - lse;
  }
}

extern "C" void kernel_launch(void* const* d_in, const int* in_sizes, int n_in,
                              void* d_out, int out_size, void* d_ws, size_t ws_size,
                              hipStream_t stream) {
  (void)in_sizes; (void)out_size;
  if (n_in < 25) return;
  const float* emb    = (const float*)d_in[0];
  const float* cWihF  = (const float*)d_in[1];
  const float* cWhhF  = (const float*)d_in[2];
  const float* cbF    = (const float*)d_in[3];
  const float* cWihB  = (const float*)d_in[4];
  const float* cWhhB  = (const float*)d_in[5];
  const float* cbB    = (const float*)d_in[6];
  const float* aWihF  = (const float*)d_in[7];
  const float* aWhhF  = (const float*)d_in[8];
  const float* abF    = (const float*)d_in[9];
  const float* aWihB  = (const float*)d_in[10];
  const float* aWhhB  = (const float*)d_in[11];
  const float* abB    = (const float*)d_in[12];
  const float* WfullF = (const float*)d_in[13];
  const float* WfullB = (const float*)d_in[14];
  const float* WmaxpF = (const float*)d_in[15];
  const float* WmaxpB = (const float*)d_in[16];
  const float* WattnF = (const float*)d_in[17];
  const float* WmaxaF = (const float*)d_in[18];
  const float* pW1    = (const float*)d_in[19];
  const float* pb1    = (const float*)d_in[20];
  const float* pW2    = (const float*)d_in[21];
  const float* pb2    = (const float*)d_in[22];
  const int*   sa     = (const int*)d_in[23];
  const int*   sb     = (const int*)d_in[24];
  float* out = (float*)d_out;
  float* ws = (float*)d_ws;

  // ---- workspace layout (float offsets) ----
  if (ws_size < (size_t)18041088 * 4) return;   // fail visibly if scratch too small
  float* WT_cihF = ws + 0;
  float* WT_cihB = ws + 360000;
  float* WT_chhF = ws + 720000;
  float* WT_chhB = ws + 1080000;
  float* WT_aihF = ws + 1440000;
  float* WT_aihB = ws + 1632000;
  float* WT_ahhF = ws + 1824000;
  float* WT_ahhB = ws + 2184000;
  float* W1T     = ws + 2544000;
  float* WG_chhF = ws + 3264000;
  float* WG_chhB = ws + 3624000;
  float* WG_ahhF = ws + 3984000;
  float* WG_ahhB = ws + 4344000;
  float* XG   = ws + 4704000;          // 4 * 2048 * 1200
  float* PAIR = XG;                    // alias (XG dead during matching)
  float* MM   = XG + 3276800;          // alias
  float* O    = ws + 14534400;         // 4 * 2048 * 300
  float* SH   = ws + 16992000;         // 2 * 38400 (double-buffered H)
  float* SC   = SH + 76800;            // 38400
  float* NRM  = ws + 17107200;
  float* COS  = ws + 17115392;
  float* RS   = ws + 17377536;
  float* CS   = ws + 17381632;
  float* V1   = ws + 17385728;
  float* V2   = V1 + 327680;

  // ---- weight prep ----
  k_transpose<<<dim3(10, 38), 256, 0, stream>>>(cWihF, WT_cihF, 1200, 300);
  k_transpose<<<dim3(10, 38), 256, 0, stream>>>(cWihB, WT_cihB, 1200, 300);
  k_transpose<<<dim3(10, 38), 256, 0, stream>>>(cWhhF, WT_chhF, 1200, 300);
  k_transpose<<<dim3(10, 38), 256, 0, stream>>>(cWhhB, WT_chhB, 1200, 300);
  k_transpose<<<dim3(5, 38), 256, 0, stream>>>(aWihF, WT_aihF, 1200, 160);
  k_transpose<<<dim3(5, 38), 256, 0, stream>>>(aWihB, WT_aihB, 1200, 160);
  k_transpose<<<dim3(10, 38), 256, 0, stream>>>(aWhhF, WT_ahhF, 1200, 300);
  k_transpose<<<dim3(10, 38), 256, 0, stream>>>(aWhhB, WT_ahhB, 1200, 300);
  k_transpose<<<dim3(38, 19), 256, 0, stream>>>(pW1, W1T, 600, 1200);
  k_gateilv<<<352, 256, 0, stream>>>(WT_chhF, WG_chhF);
  k_gateilv<<<352, 256, 0, stream>>>(WT_chhB, WG_chhB);
  k_gateilv<<<352, 256, 0, stream>>>(WT_ahhF, WG_ahhF);
  k_gateilv<<<352, 256, 0, stream>>>(WT_ahhB, WG_ahhB);

  // ---- context BiLSTM ----
  k_proj<<<dim3(32, 19), 256, 0, stream>>>(emb, sa, WT_cihF, cbF, XG + 0,       2048, 1200, 300, 300);
  k_proj<<<dim3(32, 19), 256, 0, stream>>>(emb, sa, WT_cihB, cbB, XG + 2457600, 2048, 1200, 300, 300);
  k_proj<<<dim3(32, 19), 256, 0, stream>>>(emb, sb, WT_cihF, cbF, XG + 4915200, 2048, 1200, 300, 300);
  k_proj<<<dim3(32, 19), 256, 0, stream>>>(emb, sb, WT_cihB, cbB, XG + 7372800, 2048, 1200, 300, 300);
  hipMemsetAsync(SH, 0, (size_t)115200 * 4, stream);
  for (int t = 0; t < 64; ++t)
    k_lstm<<<dim3(5, 4, 8), 256, 0, stream>>>(XG, WG_chhF, WG_chhB, SH, SC, O, t, t & 1);

  // ---- matching ----
  k_norms<<<2048, 256, 0, stream>>>(O, NRM);
  k_cos<<<dim3(32, 2), 256, 0, stream>>>(O, NRM, COS);
  k_csum<<<dim3(32, 2), 64, 0, stream>>>(COS, RS, CS);
  k_pair<<<dim3(32, 20, 2), 256, 0, stream>>>(O, NRM, WmaxpF, WmaxpB, PAIR);
  k_pairmaxJ<<<dim3(32, 20, 2), 256, 0, stream>>>(PAIR, V1);
  k_pairmaxI<<<dim3(32, 20, 2), 64, 0, stream>>>(PAIR, V2);
  k_meanmax<<<dim3(32, 8, 8), 128, 0, stream>>>(O, COS, RS, CS, MM);
  k_fullmatch<<<dim3(512, 12), 256, 0, stream>>>(O, MM, WfullF, WfullB, WattnF, WmaxaF, V1, V2);

  // ---- aggregation BiLSTM ----
  k_proj<<<dim3(32, 19), 256, 0, stream>>>(V1, nullptr, WT_aihF, abF, XG + 0,       2048, 1200, 160, 160);
  k_proj<<<dim3(32, 19), 256, 0, stream>>>(V1, nullptr, WT_aihB, abB, XG + 2457600, 2048, 1200, 160, 160);
  k_proj<<<dim3(32, 19), 256, 0, stream>>>(V2, nullptr, WT_aihF, abF, XG + 4915200, 2048, 1200, 160, 160);
  k_proj<<<dim3(32, 19), 256, 0, stream>>>(V2, nullptr, WT_aihB, abB, XG + 7372800, 2048, 1200, 160, 160);
  hipMemsetAsync(SH, 0, (size_t)115200 * 4, stream);
  for (int t = 0; t < 64; ++t)
    k_lstm<<<dim3(5, 4, 8), 256, 0, stream>>>(XG, WG_ahhF, WG_ahhB, SH, SC, nullptr, t, t & 1);

  // ---- prediction head ----
  k_mlp<<<32, 256, 0, stream>>>(SH, W1T, pb1, pW2, pb2, out);
}

// Round 2
// 2294.186 us; speedup vs baseline: 1.1689x; 1.1689x over previous
//
#include <hip/hip_runtime.h>
#include <math.h>

#define B_ 32
#define S_ 64
#define H_ 300
#define M_ 2048          // B*S
#define EPSF 1e-8f

typedef _Float16 f16;
typedef _Float16 f16x4 __attribute__((ext_vector_type(4)));
typedef _Float16 f16x8 __attribute__((ext_vector_type(8)));
typedef float f32x4 __attribute__((ext_vector_type(4)));

// ---------------- transpose (R x C) -> (C x R) ----------------
__global__ __launch_bounds__(256) void k_transpose(const float* __restrict__ src,
        float* __restrict__ dst, int R, int C) {
  __shared__ float t[32][33];
  int tx = threadIdx.x & 31, ty = threadIdx.x >> 5;
  int c0 = blockIdx.x * 32, r0 = blockIdx.y * 32;
  #pragma unroll
  for (int q = 0; q < 4; ++q) {
    int r = r0 + ty + q * 8, c = c0 + tx;
    t[ty + q * 8][tx] = (r < R && c < C) ? src[(size_t)r * C + c] : 0.f;
  }
  __syncthreads();
  #pragma unroll
  for (int q = 0; q < 4; ++q) {
    int c = c0 + ty + q * 8, r = r0 + tx;
    if (c < C && r < R) dst[(size_t)c * R + r] = t[tx][ty + q * 8];
  }
}

// ---- Whh (1200x300 f32) -> f16 padded [4 g][320 u][320 k], zeros outside ----
__global__ __launch_bounds__(256) void k_wh16(const float* __restrict__ W,
        f16* __restrict__ D) {
  int idx = blockIdx.x * 256 + threadIdx.x;
  if (idx >= 409600) return;
  int g = idx / 102400, rem = idx - g * 102400;
  int u = rem / 320, k = rem - u * 320;
  float v = (u < 300 && k < 300) ? W[((size_t)g * 300 + u) * 300 + k] : 0.f;
  D[idx] = (f16)v;
}

// ---------------- input-projection GEMM, scatter to fragment layout --------
// z[m,n] = sum_k A[row(m),k]*WT[k,n] + bias[n]; scattered into
// XG2[rec][t][jb][g][mt][nh][l][r]  (t time-reversed if rev)
__global__ __launch_bounds__(256) void k_proj(const float* __restrict__ A,
        const int* __restrict__ gather, const float* __restrict__ WT,
        const float* __restrict__ bias, float* __restrict__ XG2,
        int N, int K, int lda, int rec, int rev) {
  __shared__ float As[16][66];
  __shared__ float Bs[16][66];
  int tid = threadIdx.x;
  int m0 = blockIdx.x * 64, n0 = blockIdx.y * 64;
  int tx = tid & 15, ty = tid >> 4;
  int ar = tid >> 2, ac = (tid & 3) * 4;
  int br = tid >> 4, bc = (tid & 15) * 4;
  int gm = m0 + ar;
  const float* Arow = gather ? (A + (size_t)gather[gm] * lda)
                             : (A + (size_t)gm * lda);
  float acc[4][4] = {};
  int nk = (K + 15) / 16;
  for (int kc = 0; kc < nk; ++kc) {
    int k0 = kc * 16;
    if (k0 + 16 <= K) {
      float4 av = *(const float4*)(Arow + k0 + ac);
      As[ac + 0][ar] = av.x; As[ac + 1][ar] = av.y;
      As[ac + 2][ar] = av.z; As[ac + 3][ar] = av.w;
    } else {
      #pragma unroll
      for (int q = 0; q < 4; ++q) {
        int k = k0 + ac + q;
        As[ac + q][ar] = (k < K) ? Arow[k] : 0.f;
      }
    }
    {
      int kk = k0 + br, n = n0 + bc;
      if (kk < K && n + 3 < N) {
        float4 bv = *(const float4*)(WT + (size_t)kk * N + n);
        Bs[br][bc + 0] = bv.x; Bs[br][bc + 1] = bv.y;
        Bs[br][bc + 2] = bv.z; Bs[br][bc + 3] = bv.w;
      } else {
        #pragma unroll
        for (int q = 0; q < 4; ++q) {
          int n2 = n + q;
          Bs[br][bc + q] = (kk < K && n2 < N) ? WT[(size_t)kk * N + n2] : 0.f;
        }
      }
    }
    __syncthreads();
    #pragma unroll
    for (int kk = 0; kk < 16; ++kk) {
      float av[4], bv[4];
      #pragma unroll
      for (int i = 0; i < 4; ++i) av[i] = As[kk][ty * 4 + i];
      #pragma unroll
      for (int j = 0; j < 4; ++j) bv[j] = Bs[kk][tx * 4 + j];
      #pragma unroll
      for (int i = 0; i < 4; ++i)
        #pragma unroll
        for (int j = 0; j < 4; ++j) acc[i][j] += av[i] * bv[j];
    }
    __syncthreads();
  }
  #pragma unroll
  for (int i = 0; i < 4; ++i) {
    int m = m0 + ty * 4 + i;
    int b = m >> 6, s = m & 63;
    int t = rev ? 63 - s : s;
    int mt = b >> 4, brr = b & 15;
    int lhi = brr >> 2, r = brr & 3;
    #pragma unroll
    for (int j = 0; j < 4; ++j) {
      int n = n0 + tx * 4 + j;
      if (n < N) {
        float v = acc[i][j] + bias[n];
        int g = n / 300, u = n - g * 300;
        int jbx = u >> 5, ul = u & 31;
        int nh = ul >> 4, lo = ul & 15;
        int l = lo + lhi * 16;
        size_t off = ((((((size_t)rec * 64 + t) * 10 + jbx) * 4 + g) * 2 + mt) * 2 + nh) * 256
                     + l * 4 + r;
        XG2[off] = v;
      }
    }
  }
}

// ---------------- persistent MFMA LSTM (4 recurrences, 64 steps) ----------
// grid 40 blocks: rec = bid&3, jb = bid>>2 (u-tile of 32).
// Wh: f16 [2 dir][4 g][320][320]; XG2: [4][64][10][4][2][2][64][4] f32
// H: f16 [2 buf][4 rec][32 b][320 u]; cnt: per-rec arrival counters.
__global__ __launch_bounds__(256) void k_lstm_pers(
    const f16* __restrict__ Wh, const float* __restrict__ XG2,
    f16* __restrict__ H, float* __restrict__ O,
    unsigned int* __restrict__ cnt) {
  int bid = blockIdx.x;
  int rec = bid & 3, jb = bid >> 2;
  int tid = threadIdx.x;
  int w = tid >> 6, l = tid & 63;
  int lo = l & 15, hi = l >> 4;

  __shared__ float Zs[4][32][33];
  __shared__ float Cs[32][33];

  // persistent weight B-fragments in registers (loaded once)
  const f16* Wd = Wh + (size_t)(rec & 1) * 409600;
  f16x8 Bf[2][10];
  #pragma unroll
  for (int nh = 0; nh < 2; ++nh) {
    int u = jb * 32 + nh * 16 + lo;
    #pragma unroll
    for (int kt = 0; kt < 10; ++kt)
      Bf[nh][kt] = *(const f16x8*)(Wd + ((size_t)(w * 320 + u)) * 320 + kt * 32 + hi * 8);
  }
  for (int i = tid; i < 32 * 33; i += 256) ((float*)Cs)[i] = 0.f;
  __syncthreads();

  unsigned int* cp = cnt + rec * 32;
  int q = tid >> 5, bb = tid & 31;

  for (int t = 0; t < 64; ++t) {
    if (t > 0) {
      if (tid == 0) {
        while (__hip_atomic_load(cp, __ATOMIC_ACQUIRE, __HIP_MEMORY_SCOPE_AGENT)
               < 10u * (unsigned)t)
          __builtin_amdgcn_s_sleep(1);
      }
      __syncthreads();
      __threadfence();          // acquire: invalidate caches before reading H
    }
    const f16* Hin = H + ((size_t)(t & 1) * 4 + rec) * 10240;
    f16x8 Af[2][10];
    #pragma unroll
    for (int mt = 0; mt < 2; ++mt) {
      const f16* hp = Hin + (mt * 16 + lo) * 320 + hi * 8;
      #pragma unroll
      for (int kt = 0; kt < 10; ++kt)
        Af[mt][kt] = *(const f16x8*)(hp + kt * 32);
    }
    const float* xb = XG2 + ((((size_t)rec * 64 + t) * 10 + jb) * 4 + w) * 1024;
    f32x4 acc[2][2];
    #pragma unroll
    for (int mt = 0; mt < 2; ++mt)
      #pragma unroll
      for (int nh = 0; nh < 2; ++nh)
        acc[mt][nh] = *(const f32x4*)(xb + (mt * 2 + nh) * 256 + l * 4);
    #pragma unroll
    for (int kt = 0; kt < 10; ++kt)
      #pragma unroll
      for (int mt = 0; mt < 2; ++mt)
        #pragma unroll
        for (int nh = 0; nh < 2; ++nh)
          acc[mt][nh] = __builtin_amdgcn_mfma_f32_16x16x32_f16(
              Af[mt][kt], Bf[nh][kt], acc[mt][nh], 0, 0, 0);
    #pragma unroll
    for (int mt = 0; mt < 2; ++mt)
      #pragma unroll
      for (int nh = 0; nh < 2; ++nh)
        #pragma unroll
        for (int r = 0; r < 4; ++r)
          Zs[w][nh * 16 + lo][mt * 16 + hi * 4 + r] = acc[mt][nh][r];
    __syncthreads();

    // gates: thread handles b=bb, u = 4q..4q+3
    f16* Hout = H + ((size_t)((t + 1) & 1) * 4 + rec) * 10240 + bb * 320 + jb * 32 + q * 4;
    f16x4 hv;
    float ho[4];
    #pragma unroll
    for (int p = 0; p < 4; ++p) {
      int u = q * 4 + p;
      float zi = Zs[0][u][bb], zf = Zs[1][u][bb];
      float zg = Zs[2][u][bb], zo = Zs[3][u][bb];
      float c = Cs[u][bb];
      float si = 1.f / (1.f + expf(-zi));
      float sf = 1.f / (1.f + expf(-zf));
      float so = 1.f / (1.f + expf(-zo));
      float cn = sf * c + si * tanhf(zg);
      float hn = so * tanhf(cn);
      Cs[u][bb] = cn;
      hv[p] = (f16)hn;
      ho[p] = hn;
    }
    *(f16x4*)Hout = hv;
    if (O) {
      int ug = jb * 32 + q * 4;
      if (ug < 300) {
        int tt = (rec & 1) ? 63 - t : t;
        float4 v = make_float4(ho[0], ho[1], ho[2], ho[3]);
        *(float4*)(O + ((size_t)rec * 2048 + bb * 64 + tt) * 300 + ug) = v;
      }
    }
    __threadfence();            // release: h writes visible device-wide
    __syncthreads();
    if (tid == 0) atomicAdd(cp, 1u);
  }
}

// ---------------- plain L2 norms of the 4 ctx outputs ----------------
__global__ __launch_bounds__(256) void k_norms(const float* __restrict__ O,
        float* __restrict__ NRM) {
  int idx = blockIdx.x * 4 + (threadIdx.x >> 6);
  int lane = threadIdx.x & 63;
  const float* p = O + (size_t)idx * 300;
  float s = 0.f;
  for (int h = lane; h < 300; h += 64) { float v = p[h]; s += v * v; }
  #pragma unroll
  for (int off = 32; off; off >>= 1) s += __shfl_xor(s, off);
  if (lane == 0) NRM[idx] = sqrtf(s);
}

// ---------------- cosine matrices ----------------
__global__ __launch_bounds__(256) void k_cos(const float* __restrict__ O,
        const float* __restrict__ NRM, float* __restrict__ COS) {
  int b = blockIdx.x, d = blockIdx.y;
  int r1 = d, r2 = 2 + d;
  const float* A = O + ((size_t)r1 * M_ + b * S_) * 300;
  const float* Bm = O + ((size_t)r2 * M_ + b * S_) * 300;
  __shared__ float As[64][33], Bs[64][33];
  int tid = threadIdx.x;
  int tx = tid & 15, ty = tid >> 4;
  int lr = tid >> 2, lc = (tid & 3) * 8;
  float acc[4][4] = {};
  for (int k0 = 0; k0 < 300; k0 += 32) {
    if (k0 + 32 <= 300) {
      float4 a0 = *(const float4*)(A + (size_t)lr * 300 + k0 + lc);
      float4 a1 = *(const float4*)(A + (size_t)lr * 300 + k0 + lc + 4);
      As[lr][lc + 0] = a0.x; As[lr][lc + 1] = a0.y; As[lr][lc + 2] = a0.z; As[lr][lc + 3] = a0.w;
      As[lr][lc + 4] = a1.x; As[lr][lc + 5] = a1.y; As[lr][lc + 6] = a1.z; As[lr][lc + 7] = a1.w;
      float4 b0 = *(const float4*)(Bm + (size_t)lr * 300 + k0 + lc);
      float4 b1 = *(const float4*)(Bm + (size_t)lr * 300 + k0 + lc + 4);
      Bs[lr][lc + 0] = b0.x; Bs[lr][lc + 1] = b0.y; Bs[lr][lc + 2] = b0.z; Bs[lr][lc + 3] = b0.w;
      Bs[lr][lc + 4] = b1.x; Bs[lr][lc + 5] = b1.y; Bs[lr][lc + 6] = b1.z; Bs[lr][lc + 7] = b1.w;
    } else {
      #pragma unroll
      for (int q = 0; q < 8; ++q) {
        int k = k0 + lc + q;
        As[lr][lc + q] = (k < 300) ? A[(size_t)lr * 300 + k] : 0.f;
        Bs[lr][lc + q] = (k < 300) ? Bm[(size_t)lr * 300 + k] : 0.f;
      }
    }
    __syncthreads();
    #pragma unroll
    for (int kk = 0; kk < 32; ++kk) {
      float av[4], bv[4];
      #pragma unroll
      for (int i = 0; i < 4; ++i) av[i] = As[ty * 4 + i][kk];
      #pragma unroll
      for (int j = 0; j < 4; ++j) bv[j] = Bs[tx * 4 + j][kk];
      #pragma unroll
      for (int i = 0; i < 4; ++i)
        #pragma unroll
        for (int j = 0; j < 4; ++j) acc[i][j] += av[i] * bv[j];
    }
    __syncthreads();
  }
  float n1[4], n2[4];
  #pragma unroll
  for (int i = 0; i < 4; ++i) {
    n1[i] = NRM[(size_t)r1 * M_ + b * S_ + ty * 4 + i];
    n2[i] = NRM[(size_t)r2 * M_ + b * S_ + tx * 4 + i];
  }
  float* outp = COS + ((size_t)d * 32 + b) * 4096;
  #pragma unroll
  for (int i = 0; i < 4; ++i)
    #pragma unroll
    for (int j = 0; j < 4; ++j)
      outp[(ty * 4 + i) * 64 + tx * 4 + j] = acc[i][j] / (n1[i] * n2[j]);
}

// ---------------- cos row/col sums ----------------
__global__ __launch_bounds__(64) void k_csum(const float* __restrict__ COS,
        float* __restrict__ RS, float* __restrict__ CS) {
  int b = blockIdx.x, d = blockIdx.y, t = threadIdx.x;
  const float* base = COS + ((size_t)d * 32 + b) * 4096;
  float rs = 0.f, cs = 0.f;
  for (int k = 0; k < 64; ++k) { rs += base[t * 64 + k]; cs += base[k * 64 + t]; }
  RS[(d * 32 + b) * 64 + t] = rs;
  CS[(d * 32 + b) * 64 + t] = cs;
}

// ---------------- pairwise match (normalized), PAIR[d][b][l][i][j] ----------------
__global__ __launch_bounds__(256) void k_pair(const float* __restrict__ O,
        const float* __restrict__ NRM, const float* __restrict__ Wf,
        const float* __restrict__ Wb, float* __restrict__ PAIR) {
  int b = blockIdx.x, lidx = blockIdx.y, d = blockIdx.z;
  int r1 = d;
  const float* A = O + ((size_t)r1 * M_ + b * S_) * 300;
  const float* Bm = O + ((size_t)3 * M_ + b * S_) * 300;
  const float* Wl = (d ? Wb : Wf) + (size_t)lidx * 300;
  __shared__ float As[64][33], Bs[64][33];
  int tid = threadIdx.x;
  int tx = tid & 15, ty = tid >> 4;
  int lr = tid >> 2, lc = (tid & 3) * 8;
  float acc[4][4] = {};
  for (int k0 = 0; k0 < 300; k0 += 32) {
    if (k0 + 32 <= 300) {
      float4 a0 = *(const float4*)(A + (size_t)lr * 300 + k0 + lc);
      float4 a1 = *(const float4*)(A + (size_t)lr * 300 + k0 + lc + 4);
      float4 w0 = *(const float4*)(Wl + k0 + lc);
      float4 w1 = *(const float4*)(Wl + k0 + lc + 4);
      As[lr][lc + 0] = a0.x * w0.x * w0.x; As[lr][lc + 1] = a0.y * w0.y * w0.y;
      As[lr][lc + 2] = a0.z * w0.z * w0.z; As[lr][lc + 3] = a0.w * w0.w * w0.w;
      As[lr][lc + 4] = a1.x * w1.x * w1.x; As[lr][lc + 5] = a1.y * w1.y * w1.y;
      As[lr][lc + 6] = a1.z * w1.z * w1.z; As[lr][lc + 7] = a1.w * w1.w * w1.w;
      float4 b0 = *(const float4*)(Bm + (size_t)lr * 300 + k0 + lc);
      float4 b1 = *(const float4*)(Bm + (size_t)lr * 300 + k0 + lc + 4);
      Bs[lr][lc + 0] = b0.x; Bs[lr][lc + 1] = b0.y; Bs[lr][lc + 2] = b0.z; Bs[lr][lc + 3] = b0.w;
      Bs[lr][lc + 4] = b1.x; Bs[lr][lc + 5] = b1.y; Bs[lr][lc + 6] = b1.z; Bs[lr][lc + 7] = b1.w;
    } else {
      #pragma unroll
      for (int q = 0; q < 8; ++q) {
        int k = k0 + lc + q;
        float w = (k < 300) ? Wl[k] : 0.f;
        As[lr][lc + q] = (k < 300) ? A[(size_t)lr * 300 + k] * w * w : 0.f;
        Bs[lr][lc + q] = (k < 300) ? Bm[(size_t)lr * 300 + k] : 0.f;
      }
    }
    __syncthreads();
    #pragma unroll
    for (int kk = 0; kk < 32; ++kk) {
      float av[4], bv[4];
      #pragma unroll
      for (int i = 0; i < 4; ++i) av[i] = As[ty * 4 + i][kk];
      #pragma unroll
      for (int j = 0; j < 4; ++j) bv[j] = Bs[tx * 4 + j][kk];
      #pragma unroll
      for (int i = 0; i < 4; ++i)
        #pragma unroll
        for (int j = 0; j < 4; ++j) acc[i][j] += av[i] * bv[j];
    }
    __syncthreads();
  }
  float n1[4], n2[4];
  #pragma unroll
  for (int i = 0; i < 4; ++i) {
    n1[i] = NRM[(size_t)r1 * M_ + b * S_ + ty * 4 + i];
    n2[i] = NRM[(size_t)3 * M_ + b * S_ + tx * 4 + i];
  }
  float* outp = PAIR + (((size_t)d * 32 + b) * 20 + lidx) * 4096;
  #pragma unroll
  for (int i = 0; i < 4; ++i)
    #pragma unroll
    for (int j = 0; j < 4; ++j)
      outp[(ty * 4 + i) * 64 + tx * 4 + j] = acc[i][j] / (n1[i] * n2[j]);
}

// ---------------- maxpool over j -> V1 slot, over i -> V2 slot ----------------
__global__ __launch_bounds__(256) void k_pairmaxJ(const float* __restrict__ PAIR,
        float* __restrict__ V1) {
  int b = blockIdx.x, lidx = blockIdx.y, d = blockIdx.z;
  const float* P = PAIR + (((size_t)d * 32 + b) * 20 + lidx) * 4096;
  int lane = threadIdx.x & 63, ig = threadIdx.x >> 6;
  for (int i = ig; i < 64; i += 4) {
    float v = P[i * 64 + lane];
    #pragma unroll
    for (int off = 32; off; off >>= 1) v = fmaxf(v, __shfl_xor(v, off));
    if (lane == 0) V1[((size_t)b * S_ + i) * 160 + (d ? 100 : 20) + lidx] = v;
  }
}

__global__ __launch_bounds__(64) void k_pairmaxI(const float* __restrict__ PAIR,
        float* __restrict__ V2) {
  int b = blockIdx.x, lidx = blockIdx.y, d = blockIdx.z;
  const float* P = PAIR + (((size_t)d * 32 + b) * 20 + lidx) * 4096;
  int j = threadIdx.x;
  float m = -INFINITY;
  for (int i = 0; i < 64; ++i) m = fmaxf(m, P[i * 64 + j]);
  V2[((size_t)b * S_ + j) * 160 + (d ? 100 : 20) + lidx] = m;
}

// ---------------- mean/max attention vectors MM[v][b][r][h] ----------------
__global__ __launch_bounds__(128) void k_meanmax(const float* __restrict__ O,
        const float* __restrict__ COS, const float* __restrict__ RS,
        const float* __restrict__ CS, float* __restrict__ MM) {
  int b = blockIdx.x, rg = blockIdx.y, v = blockIdx.z;
  int isMax = v >> 2, vv = v & 3;
  int d = vv & 1, s2side = vv >> 1;
  int srcrec = s2side ? 0 : 2;
  const float* SRC = O + ((size_t)srcrec * M_ + b * S_) * 300;
  const float* Cb = COS + ((size_t)d * 32 + b) * 4096;
  int tid = threadIdx.x;
  int h0 = tid, h1 = tid + 128, h2 = tid + 256;
  bool has2 = (h2 < 300);
  float init = isMax ? -INFINITY : 0.f;
  float acc[8][3];
  #pragma unroll
  for (int rr = 0; rr < 8; ++rr) { acc[rr][0] = init; acc[rr][1] = init; acc[rr][2] = init; }
  int r0 = rg * 8;
  for (int inner = 0; inner < 64; ++inner) {
    float s0 = SRC[(size_t)inner * 300 + h0];
    float s1 = SRC[(size_t)inner * 300 + h1];
    float s2v = has2 ? SRC[(size_t)inner * 300 + h2] : 0.f;
    #pragma unroll
    for (int rr = 0; rr < 8; ++rr) {
      int r = r0 + rr;
      float cv = s2side ? Cb[inner * 64 + r] : Cb[r * 64 + inner];
      if (isMax) {
        acc[rr][0] = fmaxf(acc[rr][0], cv * s0);
        acc[rr][1] = fmaxf(acc[rr][1], cv * s1);
        acc[rr][2] = fmaxf(acc[rr][2], cv * s2v);
      } else {
        acc[rr][0] += cv * s0; acc[rr][1] += cv * s1; acc[rr][2] += cv * s2v;
      }
    }
  }
  float* outp = MM + (size_t)v * 614400;
  for (int rr = 0; rr < 8; ++rr) {
    int r = r0 + rr;
    size_t o = ((size_t)b * S_ + r) * 300;
    if (isMax) {
      outp[o + h0] = acc[rr][0];
      outp[o + h1] = acc[rr][1];
      if (has2) outp[o + h2] = acc[rr][2];
    } else {
      float den = s2side ? CS[(d * 32 + b) * 64 + r] : RS[(d * 32 + b) * 64 + r];
      outp[o + h0] = acc[rr][0] / den;
      outp[o + h1] = acc[rr][1] / den;
      if (has2) outp[o + h2] = acc[rr][2] / den;
    }
  }
}

// ---------------- generic full-match (12 variants) ----------------
__global__ __launch_bounds__(256) void k_fullmatch(const float* __restrict__ O,
        const float* __restrict__ MM, const float* __restrict__ Wff,
        const float* __restrict__ Wfb, const float* __restrict__ Wat,
        const float* __restrict__ Wmx, float* __restrict__ V1, float* __restrict__ V2) {
  int item = blockIdx.x * 4 + (threadIdx.x >> 6);
  int lane = threadIdx.x & 63;
  int b = item >> 6, s = item & 63;
  int var = blockIdx.y;
  size_t ms = (size_t)b * S_ + s;
  const float* s1f = O;
  const float* s1b = O + (size_t)M_ * 300;
  const float* s2f = O + (size_t)2 * M_ * 300;
  const float* s2b = O + (size_t)3 * M_ * 300;
  const float *v1p, *v2p, *W;
  float* outp;
  switch (var) {
    case 0:  v1p = s1f + ms * 300; v2p = s2f + ((size_t)b * S_ + 63) * 300; W = Wff; outp = V1 + ms * 160 + 0;   break;
    case 1:  v1p = s1f + ms * 300; v2p = MM + (size_t)0 * 614400 + ms * 300; W = Wat; outp = V1 + ms * 160 + 40; break;
    case 2:  v1p = s1f + ms * 300; v2p = MM + (size_t)4 * 614400 + ms * 300; W = Wmx; outp = V1 + ms * 160 + 60; break;
    case 3:  v1p = s1b + ms * 300; v2p = s2b + ((size_t)b * S_ + 0) * 300;  W = Wfb; outp = V1 + ms * 160 + 80;  break;
    case 4:  v1p = s1b + ms * 300; v2p = MM + (size_t)1 * 614400 + ms * 300; W = Wat; outp = V1 + ms * 160 + 120; break;
    case 5:  v1p = s1b + ms * 300; v2p = MM + (size_t)5 * 614400 + ms * 300; W = Wmx; outp = V1 + ms * 160 + 140; break;
    case 6:  v1p = s2f + ms * 300; v2p = s1f + ((size_t)b * S_ + 63) * 300; W = Wff; outp = V2 + ms * 160 + 0;   break;
    case 7:  v1p = s2f + ms * 300; v2p = MM + (size_t)2 * 614400 + ms * 300; W = Wat; outp = V2 + ms * 160 + 40; break;
    case 8:  v1p = s2f + ms * 300; v2p = MM + (size_t)6 * 614400 + ms * 300; W = Wmx; outp = V2 + ms * 160 + 60; break;
    case 9:  v1p = s2b + ms * 300; v2p = s1b + ((size_t)b * S_ + 0) * 300;  W = Wfb; outp = V2 + ms * 160 + 80;  break;
    case 10: v1p = s2b + ms * 300; v2p = MM + (size_t)3 * 614400 + ms * 300; W = Wat; outp = V2 + ms * 160 + 120; break;
    default: v1p = s2b + ms * 300; v2p = MM + (size_t)7 * 614400 + ms * 300; W = Wmx; outp = V2 + ms * 160 + 140; break;
  }
  float av[5], bv[5], ab[5], a2[5], b2[5];
  #pragma unroll
  for (int q = 0; q < 5; ++q) {
    int h = lane + 64 * q;
    bool in = (h < 300);
    av[q] = in ? v1p[h] : 0.f;
    bv[q] = in ? v2p[h] : 0.f;
    ab[q] = av[q] * bv[q];
    a2[q] = av[q] * av[q];
    b2[q] = bv[q] * bv[q];
  }
  for (int lq = 0; lq < 20; ++lq) {
    float sn = 0.f, sa = 0.f, sb = 0.f;
    #pragma unroll
    for (int q = 0; q < 5; ++q) {
      int h = lane + 64 * q;
      if (h < 300) {
        float w = W[(size_t)lq * 300 + h];
        float w2 = w * w;
        sn += w2 * ab[q]; sa += w2 * a2[q]; sb += w2 * b2[q];
      }
    }
    #pragma unroll
    for (int off = 32; off; off >>= 1) {
      sn += __shfl_xor(sn, off);
      sa += __shfl_xor(sa, off);
      sb += __shfl_xor(sb, off);
    }
    if (lane == 0) {
      float n1 = fmaxf(sqrtf(sa), EPSF);
      float n2 = fmaxf(sqrtf(sb), EPSF);
      outp[lq] = sn / (n1 * n2);
    }
  }
}

// ---------------- final MLP + log_softmax ----------------
__global__ __launch_bounds__(256) void k_mlp(const f16* __restrict__ H16,
        const float* __restrict__ W1T, const float* __restrict__ b1,
        const float* __restrict__ W2, const float* __restrict__ b2,
        float* __restrict__ out) {
  int b = blockIdx.x, tid = threadIdx.x;
  __shared__ float mvs[1200];
  __shared__ float xs[600];
  __shared__ float red[2][4];
  for (int i = tid; i < 1200; i += 256) {
    int r = i / 300, h = i - r * 300;
    mvs[i] = (float)H16[((size_t)r * 32 + b) * 320 + h];
  }
  __syncthreads();
  for (int o = tid; o < 600; o += 256) {
    float dot = b1[o];
    for (int k = 0; k < 1200; ++k) dot += mvs[k] * W1T[(size_t)k * 600 + o];
    xs[o] = tanhf(dot);
  }
  __syncthreads();
  float p0 = 0.f, p1 = 0.f;
  for (int k = tid; k < 600; k += 256) {
    float xv = xs[k];
    p0 += xv * W2[k];
    p1 += xv * W2[600 + k];
  }
  #pragma unroll
  for (int off = 32; off; off >>= 1) { p0 += __shfl_xor(p0, off); p1 += __shfl_xor(p1, off); }
  int w = tid >> 6;
  if ((tid & 63) == 0) { red[0][w] = p0; red[1][w] = p1; }
  __syncthreads();
  if (tid == 0) {
    float l0 = red[0][0] + red[0][1] + red[0][2] + red[0][3] + b2[0];
    float l1 = red[1][0] + red[1][1] + red[1][2] + red[1][3] + b2[1];
    float m = fmaxf(l0, l1);
    float lse = m + logf(expf(l0 - m) + expf(l1 - m));
    out[b * 2 + 0] = l0 - lse;
    out[b * 2 + 1] = l1 - lse;
  }
}

extern "C" void kernel_launch(void* const* d_in, const int* in_sizes, int n_in,
                              void* d_out, int out_size, void* d_ws, size_t ws_size,
                              hipStream_t stream) {
  (void)in_sizes; (void)out_size;
  if (n_in < 25) return;
  const float* emb    = (const float*)d_in[0];
  const float* cWihF  = (const float*)d_in[1];
  const float* cWhhF  = (const float*)d_in[2];
  const float* cbF    = (const float*)d_in[3];
  const float* cWihB  = (const float*)d_in[4];
  const float* cWhhB  = (const float*)d_in[5];
  const float* cbB    = (const float*)d_in[6];
  const float* aWihF  = (const float*)d_in[7];
  const float* aWhhF  = (const float*)d_in[8];
  const float* abF    = (const float*)d_in[9];
  const float* aWihB  = (const float*)d_in[10];
  const float* aWhhB  = (const float*)d_in[11];
  const float* abB    = (const float*)d_in[12];
  const float* WfullF = (const float*)d_in[13];
  const float* WfullB = (const float*)d_in[14];
  const float* WmaxpF = (const float*)d_in[15];
  const float* WmaxpB = (const float*)d_in[16];
  const float* WattnF = (const float*)d_in[17];
  const float* WmaxaF = (const float*)d_in[18];
  const float* pW1    = (const float*)d_in[19];
  const float* pb1    = (const float*)d_in[20];
  const float* pW2    = (const float*)d_in[21];
  const float* pb2    = (const float*)d_in[22];
  const int*   sa     = (const int*)d_in[23];
  const int*   sb     = (const int*)d_in[24];
  float* out = (float*)d_out;
  float* ws = (float*)d_ws;

  // ---- workspace layout (float offsets) ----
  if (ws_size < (size_t)16561536 * 4) return;
  float* WT_cihF = ws + 0;          //  360000
  float* WT_cihB = ws + 360000;     //  360000
  float* WT_aihF = ws + 720000;     //  192000
  float* WT_aihB = ws + 912000;     //  192000
  float* W1T     = ws + 1104000;    //  720000
  f16*   Wh16    = (f16*)(ws + 1824000);       // 4 x 409600 f16 = 819200 floats
  f16*   H16     = (f16*)(ws + 2643200);       // 81920 f16 = 40960 floats
  unsigned int* cnt = (unsigned int*)(ws + 2684160);   // 128
  float* NRM  = ws + 2684288;       //    8192
  float* COS  = ws + 2692480;       //  262144
  float* RS   = ws + 2954624;       //    4096
  float* CS   = ws + 2958720;       //    4096
  float* V1   = ws + 2962816;       //  327680
  float* V2   = ws + 3290496;       //  327680
  float* XG2  = ws + 3618176;       // 10485760 (alias: PAIR, MM during matching)
  float* PAIR = XG2;                //  5242880
  float* MM   = XG2 + 3276800;      //  4915200
  float* O    = ws + 14103936;      //  2457600

  f16* WhCtx = Wh16;
  f16* WhAgg = Wh16 + (size_t)2 * 409600;

  // ---- weight prep ----
  k_transpose<<<dim3(10, 38), 256, 0, stream>>>(cWihF, WT_cihF, 1200, 300);
  k_transpose<<<dim3(10, 38), 256, 0, stream>>>(cWihB, WT_cihB, 1200, 300);
  k_transpose<<<dim3(5, 38), 256, 0, stream>>>(aWihF, WT_aihF, 1200, 160);
  k_transpose<<<dim3(5, 38), 256, 0, stream>>>(aWihB, WT_aihB, 1200, 160);
  k_transpose<<<dim3(38, 19), 256, 0, stream>>>(pW1, W1T, 600, 1200);
  k_wh16<<<1600, 256, 0, stream>>>(cWhhF, WhCtx);
  k_wh16<<<1600, 256, 0, stream>>>(cWhhB, WhCtx + 409600);
  k_wh16<<<1600, 256, 0, stream>>>(aWhhF, WhAgg);
  k_wh16<<<1600, 256, 0, stream>>>(aWhhB, WhAgg + 409600);

  // ---- context BiLSTM ----
  hipMemsetAsync(XG2, 0, (size_t)10485760 * 4, stream);
  k_proj<<<dim3(32, 19), 256, 0, stream>>>(emb, sa, WT_cihF, cbF, XG2, 1200, 300, 300, 0, 0);
  k_proj<<<dim3(32, 19), 256, 0, stream>>>(emb, sa, WT_cihB, cbB, XG2, 1200, 300, 300, 1, 1);
  k_proj<<<dim3(32, 19), 256, 0, stream>>>(emb, sb, WT_cihF, cbF, XG2, 1200, 300, 300, 2, 0);
  k_proj<<<dim3(32, 19), 256, 0, stream>>>(emb, sb, WT_cihB, cbB, XG2, 1200, 300, 300, 3, 1);
  hipMemsetAsync(H16, 0, (size_t)41088 * 4, stream);   // H16 + cnt
  k_lstm_pers<<<40, 256, 0, stream>>>(WhCtx, XG2, H16, O, cnt);

  // ---- matching ----
  k_norms<<<2048, 256, 0, stream>>>(O, NRM);
  k_cos<<<dim3(32, 2), 256, 0, stream>>>(O, NRM, COS);
  k_csum<<<dim3(32, 2), 64, 0, stream>>>(COS, RS, CS);
  k_pair<<<dim3(32, 20, 2), 256, 0, stream>>>(O, NRM, WmaxpF, WmaxpB, PAIR);
  k_pairmaxJ<<<dim3(32, 20, 2), 256, 0, stream>>>(PAIR, V1);
  k_pairmaxI<<<dim3(32, 20, 2), 64, 0, stream>>>(PAIR, V2);
  k_meanmax<<<dim3(32, 8, 8), 128, 0, stream>>>(O, COS, RS, CS, MM);
  k_fullmatch<<<dim3(512, 12), 256, 0, stream>>>(O, MM, WfullF, WfullB, WattnF, WmaxaF, V1, V2);

  // ---- aggregation BiLSTM ----
  hipMemsetAsync(XG2, 0, (size_t)10485760 * 4, stream);
  k_proj<<<dim3(32, 19), 256, 0, stream>>>(V1, nullptr, WT_aihF, abF, XG2, 1200, 160, 160, 0, 0);
  k_proj<<<dim3(32, 19), 256, 0, stream>>>(V1, nullptr, WT_aihB, abB, XG2, 1200, 160, 160, 1, 1);
  k_proj<<<dim3(32, 19), 256, 0, stream>>>(V2, nullptr, WT_aihF, abF, XG2, 1200, 160, 160, 2, 0);
  k_proj<<<dim3(32, 19), 256, 0, stream>>>(V2, nullptr, WT_aihB, abB, XG2, 1200, 160, 160, 3, 1);
  hipMemsetAsync(H16, 0, (size_t)41088 * 4, stream);
  k_lstm_pers<<<40, 256, 0, stream>>>(WhAgg, XG2, H16, nullptr, cnt);

  // ---- prediction head ----
  k_mlp<<<32, 256, 0, stream>>>(H16, W1T, pb1, pW2, pb2, out);
}